// Round 7
// baseline (327.874 us; speedup 1.0000x reference)
//
#include <hip/hip_runtime.h>
#include <hip/hip_bf16.h>

#define E_EDGES 120000
#define NUM_NODES 12000
#define N_WAVES 1875            /* E / 64 */

typedef __attribute__((ext_vector_type(8))) short bfrag;          // 8 bf16
typedef __attribute__((ext_vector_type(8))) unsigned short ushort8;
typedef __attribute__((ext_vector_type(4))) float f32x4;

#define INV_SQRT3 0.57735026918962576f
#define SQRT2_C   1.41421356237309515f
#define N_0E_C    0.14433756729740643f   /* 1/sqrt(48) */
#define NV_C      0.14433756729740643f   /* sqrt(3/48)*1/sqrt(3) = 1/sqrt(48) */
#define WSCALE    0.08838834764831845f   /* 1/sqrt(128) */

__device__ __forceinline__ unsigned short f2bf(float f) {
    union { float f; unsigned int u; } v; v.f = f;
    unsigned int r = v.u + 0x7fffu + ((v.u >> 16) & 1u);
    return (unsigned short)(r >> 16);
}

__device__ __forceinline__ ushort8 pack8(f32x4 a, f32x4 b) {
    ushort8 o;
    o[0] = f2bf(a.x); o[1] = f2bf(a.y); o[2] = f2bf(a.z); o[3] = f2bf(a.w);
    o[4] = f2bf(b.x); o[5] = f2bf(b.y); o[6] = f2bf(b.z); o[7] = f2bf(b.w);
    return o;
}

// ---- Kernel: w_emb (128 x 3072) -> Bt in fragment-consumption order.
// Tile t = 4 KB; slot c = kb*64 + quad*16 + col; elem j: k=kb*32+quad*8+j, n=t*16+col.
// In k_gemm lane l reads t*4096 + kb*1024 + l*16 -> 1KB contiguous per instr.
__global__ void k_wt(const float* __restrict__ w_emb, unsigned short* __restrict__ Bt) {
    int i = blockIdx.x * 256 + threadIdx.x;     // i = k*3072 + n
    if (i >= 128 * 3072) return;
    int k = i / 3072;
    int n = i - k * 3072;
    int t = n >> 4, col = n & 15;
    int kb = k >> 5, quad = (k >> 3) & 3, j = k & 7;
    Bt[(size_t)t * 2048 + (size_t)(kb * 64 + quad * 16 + col) * 8 + j] = f2bf(w_emb[i] * WSCALE);
}

// ---- Kernel: per-edge prep: emb bf16 [E][128], rT fp32 tiled [E/64][128][64], cnt
__global__ void k_prep(const float* __restrict__ x, const float* __restrict__ edge_attr,
                       const float* __restrict__ Yij, const int* __restrict__ edge_index,
                       unsigned short* __restrict__ emb, float* __restrict__ rT,
                       float* __restrict__ cnt) {
    int e = blockIdx.x * 256 + threadIdx.x;
    if (e >= E_EDGES) return;
    int dst = edge_index[e];
    int src = edge_index[E_EDGES + e];
    f32x4 y = *(const f32x4*)(Yij + 4 * (long)e);
    float y0 = y.x, y1a = y.y, y1b = y.z, y1c = y.w;
    const float* xd = x + (long)dst * 80;
    const float* xs = x + (long)src * 80;
    const float* ea = edge_attr + (long)e * 64;

    ushort8* embp = (ushort8*)(emb + (long)e * 128);
    float* rb = rT + (size_t)(e >> 6) * 8192 + (e & 63);

    float xsv[80];
#pragma unroll
    for (int i = 0; i < 80; i += 4) {
        f32x4 v = *(const f32x4*)(xs + i);
        xsv[i] = v.x; xsv[i + 1] = v.y; xsv[i + 2] = v.z; xsv[i + 3] = v.w;
    }
#pragma unroll
    for (int cb = 0; cb < 4; ++cb) {
        f32x4 a = *(const f32x4*)(xd + cb * 8);
        f32x4 b = *(const f32x4*)(xd + cb * 8 + 4);
        embp[cb] = pack8(a, b);
    }
#pragma unroll
    for (int cb = 0; cb < 4; ++cb) {
        f32x4 a, b;
        a.x = xsv[cb * 8 + 0]; a.y = xsv[cb * 8 + 1]; a.z = xsv[cb * 8 + 2]; a.w = xsv[cb * 8 + 3];
        b.x = xsv[cb * 8 + 4]; b.y = xsv[cb * 8 + 5]; b.z = xsv[cb * 8 + 6]; b.w = xsv[cb * 8 + 7];
        embp[4 + cb] = pack8(a, b);
    }
#pragma unroll
    for (int cb = 0; cb < 8; ++cb) {
        f32x4 a = *(const f32x4*)(ea + cb * 8);
        f32x4 b = *(const f32x4*)(ea + cb * 8 + 4);
        embp[8 + cb] = pack8(a, b);
    }
#pragma unroll
    for (int u = 0; u < 32; ++u) rb[u * 64] = xsv[u] * y0;
#pragma unroll
    for (int u = 0; u < 16; ++u)
        rb[(32 + u) * 64] =
            (xsv[32 + 3 * u] * y1a + xsv[33 + 3 * u] * y1b + xsv[34 + 3 * u] * y1c) * INV_SQRT3;
#pragma unroll
    for (int u = 0; u < 32; ++u) rb[(48 + u) * 64] = xsv[u];
#pragma unroll
    for (int j = 0; j < 48; ++j) rb[(80 + j) * 64] = xsv[32 + j] * y0;
    atomicAdd(cnt + dst, 1.0f);
}

// ---- Kernel: fused GEMM + u-contraction, register-direct B from L2.
// No LDS, no barriers. Wave = 64 edges (4 slabs of 16). 3 phases by accumulator:
//   phase 0 = {W1,W3} -> out_s ; phase 1 = {W2,W4,W5} -> out_g + t5*y1 part of out_v ;
//   phase 2 = {W6} -> v part of out_v.
__global__ __launch_bounds__(256, 2) void k_gemm(
    const unsigned short* __restrict__ emb, const unsigned short* __restrict__ Bt,
    const float* __restrict__ rT, const int* __restrict__ edge_index,
    const float* __restrict__ Yij, float* __restrict__ summed) {
    const int lane = threadIdx.x & 63;
    const int wave = threadIdx.x >> 6;
    const int phase = blockIdx.x % 3;
    const int wid = (blockIdx.x / 3) * 4 + wave;
    if (wid >= N_WAVES) return;
    const long e0 = (long)wid * 64;
    const int col = lane & 15, quad = lane >> 4;

    // A fragments: 4 slabs x 4 k-blocks, register-resident
    bfrag A[4][4];
#pragma unroll
    for (int s = 0; s < 4; ++s) {
        const unsigned short* ap = emb + (e0 + s * 16 + col) * 128 + quad * 8;
#pragma unroll
        for (int kb = 0; kb < 4; ++kb) A[s][kb] = *(const bfrag*)(ap + kb * 32);
    }

    const float* rbase = rT + (size_t)wid * 8192 + quad * 4;
    auto loadw4 = [&](int r, f32x4* w) {
        const float* p = rbase + r * 64;
#pragma unroll
        for (int s = 0; s < 4; ++s) w[s] = *(const f32x4*)(p + s * 16);
    };
    auto loadB = [&](int t, bfrag* B) {
        const char* p = (const char*)Bt + (size_t)t * 4096 + lane * 16;
#pragma unroll
        for (int kb = 0; kb < 4; ++kb) B[kb] = *(const bfrag*)(p + kb * 1024);
    };

    f32x4 z = {0.f, 0.f, 0.f, 0.f};
    auto tileC = [&](const bfrag* B, f32x4* c) {
#pragma unroll
        for (int s = 0; s < 4; ++s) c[s] = z;
#pragma unroll
        for (int kb = 0; kb < 4; ++kb)
#pragma unroll
            for (int s = 0; s < 4; ++s)
                c[s] = __builtin_amdgcn_mfma_f32_16x16x32_bf16(A[s][kb], B[kb], c[s], 0, 0, 0);
    };

    if (phase == 0) {
        // pairs p=0..47: p<32 -> tiles 2p,2p+1 (W1, row p); p>=32 -> tiles 2p+32,2p+33 (W3, row p)
        f32x4 acc0[4] = {z, z, z, z}, acc1[4] = {z, z, z, z};
        bfrag Ba[4], Bb[4], Na[4], Nb[4];
        f32x4 w[4], wn[4];
        loadB(0, Ba); loadB(1, Bb); loadw4(0, w);
#pragma unroll 1
        for (int p = 0; p < 48; ++p) {
            if (p < 47) {
                int tn = (p + 1 < 32) ? 2 * (p + 1) : 2 * (p + 1) + 32;
                loadB(tn, Na); loadB(tn + 1, Nb); loadw4(p + 1, wn);
            }
            f32x4 c[4];
            tileC(Ba, c);
#pragma unroll
            for (int s = 0; s < 4; ++s) acc0[s] += c[s] * w[s];
            tileC(Bb, c);
#pragma unroll
            for (int s = 0; s < 4; ++s) acc1[s] += c[s] * w[s];
#pragma unroll
            for (int i = 0; i < 4; ++i) { Ba[i] = Na[i]; Bb[i] = Nb[i]; w[i] = wn[i]; }
        }
#pragma unroll
        for (int s = 0; s < 4; ++s) {
            long eb = e0 + s * 16 + quad * 4;
#pragma unroll
            for (int r = 0; r < 4; ++r) {
                int d = edge_index[eb + r];
                float* base = summed + (long)d * 96;
                atomicAdd(base + col,      N_0E_C * acc0[s][r]);
                atomicAdd(base + col + 16, N_0E_C * acc1[s][r]);
            }
        }
    } else if (phase == 1) {
        // i=0..79: tiles 64+i | 128+(i-32) | 144+(i-48); w-row = i. i<48 -> acc_g, else t5.
        f32x4 accg[4] = {z, z, z, z}, acct[4] = {z, z, z, z};
        bfrag B[4], Bn[4];
        f32x4 w[4], wn[4];
        loadB(64, B); loadw4(0, w);
#pragma unroll 1
        for (int i = 0; i < 80; ++i) {
            if (i < 79) {
                int j = i + 1;
                int tn = (j < 32) ? 64 + j : (j < 48 ? 96 + j : 96 + j);
                loadB(tn, Bn); loadw4(j, wn);
            }
            f32x4 c[4];
            tileC(B, c);
            if (i < 48) {
#pragma unroll
                for (int s = 0; s < 4; ++s) accg[s] += c[s] * w[s];
            } else {
#pragma unroll
                for (int s = 0; s < 4; ++s) acct[s] += c[s] * w[s];
            }
#pragma unroll
            for (int k = 0; k < 4; ++k) { B[k] = Bn[k]; w[k] = wn[k]; }
        }
#pragma unroll
        for (int s = 0; s < 4; ++s) {
            long eb = e0 + s * 16 + quad * 4;
#pragma unroll
            for (int r = 0; r < 4; ++r) {
                long e = eb + r;
                int d = edge_index[e];
                float* base = summed + (long)d * 96;
                float y1a = Yij[4 * e + 1], y1b = Yij[4 * e + 2], y1c = Yij[4 * e + 3];
                atomicAdd(base + 32 + col, N_0E_C * accg[s][r]);
                float t5 = NV_C * acct[s][r];
                atomicAdd(base + 48 + col * 3 + 0, t5 * y1a);
                atomicAdd(base + 48 + col * 3 + 1, t5 * y1b);
                atomicAdd(base + 48 + col * 3 + 2, t5 * y1c);
            }
        }
    } else {
        // W6: u=0..15, tile 176+u, w-rows 80+3u+k -> acc_v[k]
        f32x4 accv[4][3] = {{z,z,z},{z,z,z},{z,z,z},{z,z,z}};
        bfrag B[4], Bn[4];
        loadB(176, B);
#pragma unroll 1
        for (int u = 0; u < 16; ++u) {
            if (u < 15) loadB(177 + u, Bn);
            f32x4 w0[4], w1[4], w2[4];
            loadw4(80 + 3 * u, w0); loadw4(81 + 3 * u, w1); loadw4(82 + 3 * u, w2);
            f32x4 c[4];
            tileC(B, c);
#pragma unroll
            for (int s = 0; s < 4; ++s) {
                accv[s][0] += c[s] * w0[s];
                accv[s][1] += c[s] * w1[s];
                accv[s][2] += c[s] * w2[s];
            }
#pragma unroll
            for (int k = 0; k < 4; ++k) B[k] = Bn[k];
        }
#pragma unroll
        for (int s = 0; s < 4; ++s) {
            long eb = e0 + s * 16 + quad * 4;
#pragma unroll
            for (int r = 0; r < 4; ++r) {
                int d = edge_index[eb + r];
                float* base = summed + (long)d * 96;
                atomicAdd(base + 48 + col * 3 + 0, NV_C * accv[s][0][r]);
                atomicAdd(base + 48 + col * 3 + 1, NV_C * accv[s][1][r]);
                atomicAdd(base + 48 + col * 3 + 2, NV_C * accv[s][2][r]);
            }
        }
    }
}

// ---- Kernel: mean, relu-gate, residual
__global__ void k_final(const float* __restrict__ x, const float* __restrict__ summed,
                        const float* __restrict__ cnt, float* __restrict__ out) {
    int tid = blockIdx.x * 256 + threadIdx.x;
    if (tid >= NUM_NODES * 80) return;
    int n = tid / 80, c = tid % 80;
    float m = fmaxf(cnt[n], 1.0f);
    float inv = 1.0f / m;
    float val;
    if (c < 32) {
        val = SQRT2_C * fmaxf(summed[(long)n * 96 + c] * inv, 0.0f);
    } else {
        int j = c - 32;
        int w = j / 3;
        float g = SQRT2_C * fmaxf(summed[(long)n * 96 + 32 + w] * inv, 0.0f);
        val = summed[(long)n * 96 + 48 + j] * inv * g;
    }
    out[tid] = x[tid] + val;
}

extern "C" void kernel_launch(void* const* d_in, const int* in_sizes, int n_in,
                              void* d_out, int out_size, void* d_ws, size_t ws_size,
                              hipStream_t stream) {
    const float* x         = (const float*)d_in[0];
    const float* edge_attr = (const float*)d_in[1];
    const float* Yij       = (const float*)d_in[2];
    const int*   edge_index= (const int*)d_in[3];
    const float* w_emb     = (const float*)d_in[4];
    float* out = (float*)d_out;

    char* ws = (char*)d_ws;
    size_t off = 0;
    unsigned short* emb = (unsigned short*)(ws + off); off += (size_t)E_EDGES * 128 * 2;
    unsigned short* Bt  = (unsigned short*)(ws + off); off += (size_t)3072 * 128 * 2;
    off = (off + 255) & ~(size_t)255;
    float* rT     = (float*)(ws + off); off += (size_t)N_WAVES * 8192 * 4;
    size_t zoff = off;
    float* summed = (float*)(ws + off); off += (size_t)NUM_NODES * 96 * 4;
    float* cnt    = (float*)(ws + off); off += (size_t)NUM_NODES * 4;

    hipMemsetAsync(ws + zoff, 0, (size_t)NUM_NODES * 97 * 4, stream);
    k_wt  <<<(128 * 3072 + 255) / 256, 256, 0, stream>>>(w_emb, Bt);
    k_prep<<<(E_EDGES + 255) / 256, 256, 0, stream>>>(x, edge_attr, Yij, edge_index, emb, rT, cnt);
    int blocks_per_phase = (N_WAVES + 3) / 4;     // 469
    k_gemm<<<3 * blocks_per_phase, 256, 0, stream>>>(emb, Bt, rT, edge_index, Yij, summed);
    k_final<<<(NUM_NODES * 80 + 255) / 256, 256, 0, stream>>>(x, summed, cnt, out);
}

// Round 8
// 321.416 us; speedup vs baseline: 1.0201x; 1.0201x over previous
//
#include <hip/hip_runtime.h>
#include <hip/hip_bf16.h>

#define E_EDGES 120000
#define NUM_NODES 12000
#define N_GROUPS 469            /* ceil(E/256) */

typedef __attribute__((ext_vector_type(8))) short bfrag;          // 8 bf16
typedef __attribute__((ext_vector_type(8))) unsigned short ushort8;
typedef __attribute__((ext_vector_type(4))) float f32x4;

#define INV_SQRT3 0.57735026918962576f
#define SQRT2_C   1.41421356237309515f
#define N_0E_C    0.14433756729740643f   /* 1/sqrt(48) */
#define NV_C      0.14433756729740643f   /* sqrt(3/48)*1/sqrt(3) = 1/sqrt(48) */
#define WSCALE    0.08838834764831845f   /* 1/sqrt(128) */

__device__ __forceinline__ unsigned short f2bf(float f) {
    union { float f; unsigned int u; } v; v.f = f;
    unsigned int r = v.u + 0x7fffu + ((v.u >> 16) & 1u);
    return (unsigned short)(r >> 16);
}

__device__ __forceinline__ ushort8 pack8(f32x4 a, f32x4 b) {
    ushort8 o;
    o[0] = f2bf(a.x); o[1] = f2bf(a.y); o[2] = f2bf(a.z); o[3] = f2bf(a.w);
    o[4] = f2bf(b.x); o[5] = f2bf(b.y); o[6] = f2bf(b.z); o[7] = f2bf(b.w);
    return o;
}

// ---- Kernel: w_emb (128 x 3072) -> Bt in fragment-consumption order.
__global__ void k_wt(const float* __restrict__ w_emb, unsigned short* __restrict__ Bt) {
    int i = blockIdx.x * 256 + threadIdx.x;     // i = k*3072 + n
    if (i >= 128 * 3072) return;
    int k = i / 3072;
    int n = i - k * 3072;
    int t = n >> 4, col = n & 15;
    int kb = k >> 5, quad = (k >> 3) & 3, j = k & 7;
    Bt[(size_t)t * 2048 + (size_t)(kb * 64 + quad * 16 + col) * 8 + j] = f2bf(w_emb[i] * WSCALE);
}

// ---- Kernel: per-edge prep: emb bf16 [E][128], rT fp32 tiled [E/64][128][64], cnt
__global__ void k_prep(const float* __restrict__ x, const float* __restrict__ edge_attr,
                       const float* __restrict__ Yij, const int* __restrict__ edge_index,
                       unsigned short* __restrict__ emb, float* __restrict__ rT,
                       float* __restrict__ cnt) {
    int e = blockIdx.x * 256 + threadIdx.x;
    if (e >= E_EDGES) return;
    int dst = edge_index[e];
    int src = edge_index[E_EDGES + e];
    f32x4 y = *(const f32x4*)(Yij + 4 * (long)e);
    float y0 = y.x, y1a = y.y, y1b = y.z, y1c = y.w;
    const float* xd = x + (long)dst * 80;
    const float* xs = x + (long)src * 80;
    const float* ea = edge_attr + (long)e * 64;

    ushort8* embp = (ushort8*)(emb + (long)e * 128);
    float* rb = rT + (size_t)(e >> 6) * 8192 + (e & 63);

    float xsv[80];
#pragma unroll
    for (int i = 0; i < 80; i += 4) {
        f32x4 v = *(const f32x4*)(xs + i);
        xsv[i] = v.x; xsv[i + 1] = v.y; xsv[i + 2] = v.z; xsv[i + 3] = v.w;
    }
#pragma unroll
    for (int cb = 0; cb < 4; ++cb) {
        f32x4 a = *(const f32x4*)(xd + cb * 8);
        f32x4 b = *(const f32x4*)(xd + cb * 8 + 4);
        embp[cb] = pack8(a, b);
    }
#pragma unroll
    for (int cb = 0; cb < 4; ++cb) {
        f32x4 a, b;
        a.x = xsv[cb * 8 + 0]; a.y = xsv[cb * 8 + 1]; a.z = xsv[cb * 8 + 2]; a.w = xsv[cb * 8 + 3];
        b.x = xsv[cb * 8 + 4]; b.y = xsv[cb * 8 + 5]; b.z = xsv[cb * 8 + 6]; b.w = xsv[cb * 8 + 7];
        embp[4 + cb] = pack8(a, b);
    }
#pragma unroll
    for (int cb = 0; cb < 8; ++cb) {
        f32x4 a = *(const f32x4*)(ea + cb * 8);
        f32x4 b = *(const f32x4*)(ea + cb * 8 + 4);
        embp[8 + cb] = pack8(a, b);
    }
#pragma unroll
    for (int u = 0; u < 32; ++u) rb[u * 64] = xsv[u] * y0;
#pragma unroll
    for (int u = 0; u < 16; ++u)
        rb[(32 + u) * 64] =
            (xsv[32 + 3 * u] * y1a + xsv[33 + 3 * u] * y1b + xsv[34 + 3 * u] * y1c) * INV_SQRT3;
#pragma unroll
    for (int u = 0; u < 32; ++u) rb[(48 + u) * 64] = xsv[u];
#pragma unroll
    for (int j = 0; j < 48; ++j) rb[(80 + j) * 64] = xsv[32 + j] * y0;
    atomicAdd(cnt + dst, 1.0f);
}

// ---- Kernel: fused GEMM + u-contraction. Block = 4 waves x 64 edges = 256 edges.
// Bt staged via LDS double-buffer DMA (16KB chunks of 4 tiles). 3 phases by
// accumulator (R7-verified split): 0={W1,W3}->out_s, 1={W2,W4,W5}->out_g+t5*y1,
// 2={W6}->v. Staged DMA volume: 469 groups x 768 KB = 360 MB.
__global__ __launch_bounds__(256, 2) void k_gemm(
    const unsigned short* __restrict__ emb, const unsigned short* __restrict__ Bt,
    const float* __restrict__ rT, const int* __restrict__ edge_index,
    const float* __restrict__ Yij, float* __restrict__ summed) {
    const int lane = threadIdx.x & 63;
    const int wave = threadIdx.x >> 6;
    const int phase = blockIdx.x % 3;
    const int grp = blockIdx.x / 3;
    long e0 = (long)grp * 256 + (long)wave * 64;
    const bool dup = (e0 + 64 > E_EDGES);
    if (dup) e0 = E_EDGES - 64;
    const int col = lane & 15, quad = lane >> 4;

    __shared__ __align__(16) char lds[2][16384];

    // A fragments: 4 slabs x 4 k-blocks, register-resident
    bfrag A[4][4];
#pragma unroll
    for (int s = 0; s < 4; ++s) {
        const unsigned short* ap = emb + (e0 + s * 16 + col) * 128 + quad * 8;
#pragma unroll
        for (int kb = 0; kb < 4; ++kb) A[s][kb] = *(const bfrag*)(ap + kb * 32);
    }

    int wp = 0, rp = 0;
    auto stage = [&](int ci) {   // ci = global 16KB chunk id 0..47
        const char* g = (const char*)Bt + (size_t)ci * 16384 + wave * 4096 + lane * 16;
        char* l = &lds[(wp++) & 1][wave * 4096];
#pragma unroll
        for (int j = 0; j < 4; ++j)
            __builtin_amdgcn_global_load_lds(
                (const __attribute__((address_space(1))) unsigned int*)(g + j * 1024),
                (__attribute__((address_space(3))) unsigned int*)(l + j * 1024), 16, 0, 0);
    };
    auto nextbuf = [&](int nxt) -> const char* {
        __syncthreads();
        if (nxt >= 0) stage(nxt);
        return lds[(rp++) & 1];
    };

    f32x4 z = {0.f, 0.f, 0.f, 0.f};
    const float* rbase = rT + (size_t)(e0 >> 6) * 8192 + quad * 4;
    auto loadw4 = [&](int r, f32x4* w) {   // w[s] for the 4 slabs
        const float* p = rbase + r * 64;
#pragma unroll
        for (int s = 0; s < 4; ++s) w[s] = *(const f32x4*)(p + s * 16);
    };

    auto tileC = [&](const char* lt, f32x4* c) {
        bfrag B0 = *(const bfrag*)(lt + lane * 16);
        bfrag B1 = *(const bfrag*)(lt + lane * 16 + 1024);
        bfrag B2 = *(const bfrag*)(lt + lane * 16 + 2048);
        bfrag B3 = *(const bfrag*)(lt + lane * 16 + 3072);
#pragma unroll
        for (int s = 0; s < 4; ++s) c[s] = z;
#pragma unroll
        for (int s = 0; s < 4; ++s) c[s] = __builtin_amdgcn_mfma_f32_16x16x32_bf16(A[s][0], B0, c[s], 0, 0, 0);
#pragma unroll
        for (int s = 0; s < 4; ++s) c[s] = __builtin_amdgcn_mfma_f32_16x16x32_bf16(A[s][1], B1, c[s], 0, 0, 0);
#pragma unroll
        for (int s = 0; s < 4; ++s) c[s] = __builtin_amdgcn_mfma_f32_16x16x32_bf16(A[s][2], B2, c[s], 0, 0, 0);
#pragma unroll
        for (int s = 0; s < 4; ++s) c[s] = __builtin_amdgcn_mfma_f32_16x16x32_bf16(A[s][3], B3, c[s], 0, 0, 0);
    };

    f32x4 c[4];

    if (phase == 0) {
        // 24 chunks: i<16 -> chunk i (W1, u-pair 2i,2i+1, rows 2i,2i+1);
        //            i>=16 -> chunk 24+(i-16) (W3, rows 32+2(i-16), 33+2(i-16)).
        f32x4 acc0[4] = {z, z, z, z}, acc1[4] = {z, z, z, z};
        f32x4 wA[4], wB[4], nA[4], nB[4];
        stage(0);
        loadw4(0, wA); loadw4(1, wB);
#pragma unroll 1
        for (int i = 0; i < 24; ++i) {
            int nchunk = (i < 15) ? i + 1 : (i < 23 ? 24 + (i - 15) : -1);
            const char* buf = nextbuf(nchunk);
            int nr = (i < 15) ? 2 * i + 2 : (i < 23 ? 32 + 2 * (i - 15) : 0);
            loadw4(nr, nA); loadw4(nr + 1, nB);
            tileC(buf, c);
#pragma unroll
            for (int s = 0; s < 4; ++s) acc0[s] += c[s] * wA[s];
            tileC(buf + 4096, c);
#pragma unroll
            for (int s = 0; s < 4; ++s) acc1[s] += c[s] * wA[s];
            tileC(buf + 8192, c);
#pragma unroll
            for (int s = 0; s < 4; ++s) acc0[s] += c[s] * wB[s];
            tileC(buf + 12288, c);
#pragma unroll
            for (int s = 0; s < 4; ++s) acc1[s] += c[s] * wB[s];
#pragma unroll
            for (int s = 0; s < 4; ++s) { wA[s] = nA[s]; wB[s] = nB[s]; }
        }
        if (dup) return;
#pragma unroll
        for (int s = 0; s < 4; ++s) {
            long eb = e0 + s * 16 + quad * 4;
#pragma unroll
            for (int r = 0; r < 4; ++r) {
                int d = edge_index[eb + r];
                float* base = summed + (long)d * 96;
                atomicAdd(base + col,      N_0E_C * acc0[s][r]);
                atomicAdd(base + col + 16, N_0E_C * acc1[s][r]);
            }
        }
    } else if (phase == 1) {
        // 20 chunks: i<8 -> chunk 16+i (W2, rows 4i..4i+3) -> acc_g
        //            i in 8..11 -> chunk 32+(i-8) (W4, rows 32+4(i-8)..) -> acc_g
        //            i in 12..19 -> chunk 36+(i-12) (W5, rows 48+4(i-12)..) -> acc_t5
        f32x4 accg[4] = {z, z, z, z}, acct[4] = {z, z, z, z};
        f32x4 wA[4], wB[4], nA[4], nB[4];
        stage(16);
        loadw4(0, wA); loadw4(1, wB);   // first chunk rows 0,1 (halves: rows 0,1 then 2,3)
#pragma unroll 1
        for (int i = 0; i < 20; ++i) {
            int nchunk = (i < 7) ? 17 + i : (i < 11 ? 32 + (i - 7) : (i < 19 ? 36 + (i - 11) : -1));
            const char* buf = nextbuf(nchunk);
            int r0 = (i < 8) ? 4 * i : (i < 12 ? 32 + 4 * (i - 8) : 48 + 4 * (i - 12));
#pragma unroll
            for (int h = 0; h < 2; ++h) {
                // rows for NEXT half (or next chunk's first half)
                int nr;
                if (h == 0) nr = r0 + 2;
                else {
                    int j = i + 1;
                    nr = (j < 8) ? 4 * j : (j < 12 ? 32 + 4 * (j - 8) : (j < 20 ? 48 + 4 * (j - 12) : 0));
                }
                f32x4 cwA[4], cwB[4];
#pragma unroll
                for (int s = 0; s < 4; ++s) { cwA[s] = wA[s]; cwB[s] = wB[s]; }
                loadw4(nr, nA); loadw4(nr + 1, nB);
                tileC(buf + h * 8192, c);
                if (i < 12) {
#pragma unroll
                    for (int s = 0; s < 4; ++s) accg[s] += c[s] * cwA[s];
                } else {
#pragma unroll
                    for (int s = 0; s < 4; ++s) acct[s] += c[s] * cwA[s];
                }
                tileC(buf + h * 8192 + 4096, c);
                if (i < 12) {
#pragma unroll
                    for (int s = 0; s < 4; ++s) accg[s] += c[s] * cwB[s];
                } else {
#pragma unroll
                    for (int s = 0; s < 4; ++s) acct[s] += c[s] * cwB[s];
                }
#pragma unroll
                for (int s = 0; s < 4; ++s) { wA[s] = nA[s]; wB[s] = nB[s]; }
            }
        }
        if (dup) return;
#pragma unroll
        for (int s = 0; s < 4; ++s) {
            long eb = e0 + s * 16 + quad * 4;
#pragma unroll
            for (int r = 0; r < 4; ++r) {
                long e = eb + r;
                int d = edge_index[e];
                float* base = summed + (long)d * 96;
                float y1a = Yij[4 * e + 1], y1b = Yij[4 * e + 2], y1c = Yij[4 * e + 3];
                atomicAdd(base + 32 + col, N_0E_C * accg[s][r]);
                float t5 = NV_C * acct[s][r];
                atomicAdd(base + 48 + col * 3 + 0, t5 * y1a);
                atomicAdd(base + 48 + col * 3 + 1, t5 * y1b);
                atomicAdd(base + 48 + col * 3 + 2, t5 * y1c);
            }
        }
    } else {
        // 4 chunks 44..47 (W6): chunk i covers u = 4i..4i+3, rows 80+3u+k -> accv[k]
        f32x4 accv[4][3] = {{z,z,z},{z,z,z},{z,z,z},{z,z,z}};
        stage(44);
#pragma unroll 1
        for (int i = 0; i < 4; ++i) {
            const char* buf = nextbuf(i < 3 ? 45 + i : -1);
#pragma unroll
            for (int t = 0; t < 4; ++t) {
                int u = 4 * i + t;
                f32x4 w0[4], w1[4], w2[4];
                loadw4(80 + 3 * u, w0); loadw4(81 + 3 * u, w1); loadw4(82 + 3 * u, w2);
                tileC(buf + t * 4096, c);
#pragma unroll
                for (int s = 0; s < 4; ++s) {
                    accv[s][0] += c[s] * w0[s];
                    accv[s][1] += c[s] * w1[s];
                    accv[s][2] += c[s] * w2[s];
                }
            }
        }
        if (dup) return;
#pragma unroll
        for (int s = 0; s < 4; ++s) {
            long eb = e0 + s * 16 + quad * 4;
#pragma unroll
            for (int r = 0; r < 4; ++r) {
                int d = edge_index[eb + r];
                float* base = summed + (long)d * 96;
                atomicAdd(base + 48 + col * 3 + 0, NV_C * accv[s][0][r]);
                atomicAdd(base + 48 + col * 3 + 1, NV_C * accv[s][1][r]);
                atomicAdd(base + 48 + col * 3 + 2, NV_C * accv[s][2][r]);
            }
        }
    }
}

// ---- Kernel: mean, relu-gate, residual
__global__ void k_final(const float* __restrict__ x, const float* __restrict__ summed,
                        const float* __restrict__ cnt, float* __restrict__ out) {
    int tid = blockIdx.x * 256 + threadIdx.x;
    if (tid >= NUM_NODES * 80) return;
    int n = tid / 80, c = tid % 80;
    float m = fmaxf(cnt[n], 1.0f);
    float inv = 1.0f / m;
    float val;
    if (c < 32) {
        val = SQRT2_C * fmaxf(summed[(long)n * 96 + c] * inv, 0.0f);
    } else {
        int j = c - 32;
        int w = j / 3;
        float g = SQRT2_C * fmaxf(summed[(long)n * 96 + 32 + w] * inv, 0.0f);
        val = summed[(long)n * 96 + 48 + j] * inv * g;
    }
    out[tid] = x[tid] + val;
}

extern "C" void kernel_launch(void* const* d_in, const int* in_sizes, int n_in,
                              void* d_out, int out_size, void* d_ws, size_t ws_size,
                              hipStream_t stream) {
    const float* x         = (const float*)d_in[0];
    const float* edge_attr = (const float*)d_in[1];
    const float* Yij       = (const float*)d_in[2];
    const int*   edge_index= (const int*)d_in[3];
    const float* w_emb     = (const float*)d_in[4];
    float* out = (float*)d_out;

    char* ws = (char*)d_ws;
    size_t off = 0;
    unsigned short* emb = (unsigned short*)(ws + off); off += (size_t)E_EDGES * 128 * 2;
    unsigned short* Bt  = (unsigned short*)(ws + off); off += (size_t)3072 * 128 * 2;
    off = (off + 255) & ~(size_t)255;
    float* rT     = (float*)(ws + off); off += (size_t)(E_EDGES / 64) * 8192 * 4;
    size_t zoff = off;
    float* summed = (float*)(ws + off); off += (size_t)NUM_NODES * 96 * 4;
    float* cnt    = (float*)(ws + off); off += (size_t)NUM_NODES * 4;

    hipMemsetAsync(ws + zoff, 0, (size_t)NUM_NODES * 97 * 4, stream);
    k_wt  <<<(128 * 3072 + 255) / 256, 256, 0, stream>>>(w_emb, Bt);
    k_prep<<<(E_EDGES + 255) / 256, 256, 0, stream>>>(x, edge_attr, Yij, edge_index, emb, rT, cnt);
    k_gemm<<<3 * N_GROUPS, 256, 0, stream>>>(emb, Bt, rT, edge_index, Yij, summed);
    k_final<<<(NUM_NODES * 80 + 255) / 256, 256, 0, stream>>>(x, summed, cnt, out);
}

// Round 9
// 308.245 us; speedup vs baseline: 1.0637x; 1.0427x over previous
//
#include <hip/hip_runtime.h>
#include <hip/hip_bf16.h>

#define E_EDGES 120000
#define NUM_NODES 12000

typedef __attribute__((ext_vector_type(8))) short bfrag;          // 8 bf16
typedef __attribute__((ext_vector_type(8))) unsigned short ushort8;
typedef __attribute__((ext_vector_type(4))) float f32x4;

#define INV_SQRT3 0.57735026918962576f
#define SQRT2_C   1.41421356237309515f
#define N_0E_C    0.14433756729740643f   /* 1/sqrt(48) */
#define NV_C      0.14433756729740643f   /* sqrt(3/48)*1/sqrt(3) = 1/sqrt(48) */
#define WSCALE    0.08838834764831845f   /* 1/sqrt(128) */

__device__ __forceinline__ unsigned short f2bf(float f) {
    union { float f; unsigned int u; } v; v.f = f;
    unsigned int r = v.u + 0x7fffu + ((v.u >> 16) & 1u);
    return (unsigned short)(r >> 16);
}

__device__ __forceinline__ ushort8 pack8(f32x4 a, f32x4 b) {
    ushort8 o;
    o[0] = f2bf(a.x); o[1] = f2bf(a.y); o[2] = f2bf(a.z); o[3] = f2bf(a.w);
    o[4] = f2bf(b.x); o[5] = f2bf(b.y); o[6] = f2bf(b.z); o[7] = f2bf(b.w);
    return o;
}

// ---- w_emb (128 x 3072) -> Bt in fragment-consumption order (conflict-free LDS image)
__global__ void k_wt(const float* __restrict__ w_emb, unsigned short* __restrict__ Bt) {
    int i = blockIdx.x * 256 + threadIdx.x;     // i = k*3072 + n
    if (i >= 128 * 3072) return;
    int k = i / 3072;
    int n = i - k * 3072;
    int t = n >> 4, col = n & 15;
    int kb = k >> 5, quad = (k >> 3) & 3, j = k & 7;
    Bt[(size_t)t * 2048 + (size_t)(kb * 64 + quad * 16 + col) * 8 + j] = f2bf(w_emb[i] * WSCALE);
}

// ---- per-edge prep: emb bf16 [E][128], rT fp32 tiled [E/32][128][32], hist
__global__ void k_prep(const float* __restrict__ x, const float* __restrict__ edge_attr,
                       const float* __restrict__ Yij, const int* __restrict__ edge_index,
                       unsigned short* __restrict__ emb, float* __restrict__ rT,
                       int* __restrict__ hist) {
    int e = blockIdx.x * 256 + threadIdx.x;
    if (e >= E_EDGES) return;
    int dst = edge_index[e];
    int src = edge_index[E_EDGES + e];
    f32x4 y = *(const f32x4*)(Yij + 4 * (long)e);
    float y0 = y.x, y1a = y.y, y1b = y.z, y1c = y.w;
    const float* xd = x + (long)dst * 80;
    const float* xs = x + (long)src * 80;
    const float* ea = edge_attr + (long)e * 64;

    ushort8* embp = (ushort8*)(emb + (long)e * 128);
    float* rb = rT + (size_t)(e >> 5) * 4096 + (e & 31);

    float xsv[80];
#pragma unroll
    for (int i = 0; i < 80; i += 4) {
        f32x4 v = *(const f32x4*)(xs + i);
        xsv[i] = v.x; xsv[i + 1] = v.y; xsv[i + 2] = v.z; xsv[i + 3] = v.w;
    }
#pragma unroll
    for (int cb = 0; cb < 4; ++cb) {
        f32x4 a = *(const f32x4*)(xd + cb * 8);
        f32x4 b = *(const f32x4*)(xd + cb * 8 + 4);
        embp[cb] = pack8(a, b);
    }
#pragma unroll
    for (int cb = 0; cb < 4; ++cb) {
        f32x4 a, b;
        a.x = xsv[cb * 8 + 0]; a.y = xsv[cb * 8 + 1]; a.z = xsv[cb * 8 + 2]; a.w = xsv[cb * 8 + 3];
        b.x = xsv[cb * 8 + 4]; b.y = xsv[cb * 8 + 5]; b.z = xsv[cb * 8 + 6]; b.w = xsv[cb * 8 + 7];
        embp[4 + cb] = pack8(a, b);
    }
#pragma unroll
    for (int cb = 0; cb < 8; ++cb) {
        f32x4 a = *(const f32x4*)(ea + cb * 8);
        f32x4 b = *(const f32x4*)(ea + cb * 8 + 4);
        embp[8 + cb] = pack8(a, b);
    }
#pragma unroll
    for (int u = 0; u < 32; ++u) rb[u * 32] = xsv[u] * y0;
#pragma unroll
    for (int u = 0; u < 16; ++u)
        rb[(32 + u) * 32] =
            (xsv[32 + 3 * u] * y1a + xsv[33 + 3 * u] * y1b + xsv[34 + 3 * u] * y1c) * INV_SQRT3;
#pragma unroll
    for (int u = 0; u < 32; ++u) rb[(48 + u) * 32] = xsv[u];
#pragma unroll
    for (int j = 0; j < 48; ++j) rb[(80 + j) * 32] = xsv[32 + j] * y0;
    atomicAdd(hist + dst, 1);
}

// ---- exclusive prefix scan of hist[12000] -> off, pos (single block)
__global__ __launch_bounds__(1024) void k_scan(const int* __restrict__ hist,
                                               int* __restrict__ off, int* __restrict__ pos) {
    __shared__ int part[1024];
    int t = threadIdx.x;
    int base = t * 12;
    int loc[12];
    int s = 0;
#pragma unroll
    for (int i = 0; i < 12; ++i) {
        int idx = base + i;
        int v = (idx < NUM_NODES) ? hist[idx] : 0;
        loc[i] = s; s += v;
    }
    part[t] = s;
    __syncthreads();
    for (int ofs = 1; ofs < 1024; ofs <<= 1) {
        int v = (t >= ofs) ? part[t - ofs] : 0;
        __syncthreads();
        part[t] += v;
        __syncthreads();
    }
    int pre = (t == 0) ? 0 : part[t - 1];
#pragma unroll
    for (int i = 0; i < 12; ++i) {
        int idx = base + i;
        if (idx < NUM_NODES) { off[idx] = pre + loc[i]; pos[idx] = pre + loc[i]; }
    }
}

// ---- fill CSR edge lists
__global__ void k_fill(const int* __restrict__ edge_index, int* __restrict__ pos,
                       int* __restrict__ csr_e) {
    int e = blockIdx.x * 256 + threadIdx.x;
    if (e >= E_EDGES) return;
    int d = edge_index[e];
    int p = atomicAdd(pos + d, 1);
    csr_e[p] = e;
}

// ---- fused GEMM + u-contraction (R4 config: 4 waves x 32 edges, 48x16KB chunks,
// LDS double-buffer DMA). Epilogue: coalesced store to msg[E][96], ZERO atomics.
__global__ __launch_bounds__(256, 4) void k_gemm(
    const unsigned short* __restrict__ emb, const unsigned short* __restrict__ Bt,
    const float* __restrict__ rT, const float* __restrict__ Yij,
    float* __restrict__ msg) {
    const int lane = threadIdx.x & 63;
    const int wave = threadIdx.x >> 6;
    long e0 = (long)blockIdx.x * 128 + (long)wave * 32;
    const bool dup = (e0 + 32 > E_EDGES);
    if (dup) e0 = E_EDGES - 32;
    const int col = lane & 15, quad = lane >> 4;

    __shared__ __align__(16) char lds[2][16384];

    bfrag A[2][4];
#pragma unroll
    for (int s = 0; s < 2; ++s) {
        const unsigned short* ap = emb + (e0 + s * 16 + col) * 128 + quad * 8;
#pragma unroll
        for (int kb = 0; kb < 4; ++kb) A[s][kb] = *(const bfrag*)(ap + kb * 32);
    }

    int wp = 0, rp = 0;
    auto stage = [&](int ci) {
        const char* g = (const char*)Bt + (size_t)ci * 16384 + wave * 4096 + lane * 16;
        char* l = &lds[(wp++) & 1][wave * 4096];
#pragma unroll
        for (int j = 0; j < 4; ++j)
            __builtin_amdgcn_global_load_lds(
                (const __attribute__((address_space(1))) unsigned int*)(g + j * 1024),
                (__attribute__((address_space(3))) unsigned int*)(l + j * 1024), 16, 0, 0);
    };
    auto nextbuf = [&](int nxt) -> const char* {
        __syncthreads();
        if (nxt >= 0) stage(nxt);
        return lds[(rp++) & 1];
    };

    f32x4 z = {0.f, 0.f, 0.f, 0.f};
    f32x4 acc_s0[2] = {z, z}, acc_s1[2] = {z, z}, acc_g[2] = {z, z}, acc_t5[2] = {z, z};
    f32x4 acc_v[2][3] = {{z, z, z}, {z, z, z}};

    // tiled rT: wave's weights live in one contiguous 16 KB block
    const float* rbase = rT + (size_t)(e0 >> 5) * 4096 + quad * 4;
    auto loadw = [&](int r, f32x4& a, f32x4& b) {
        const float* p = rbase + r * 32;
        a = *(const f32x4*)(p);
        b = *(const f32x4*)(p + 16);
    };

    auto tile = [&](const char* lt, f32x4& c0, f32x4& c1) {
        bfrag B0 = *(const bfrag*)(lt + lane * 16);
        bfrag B1 = *(const bfrag*)(lt + lane * 16 + 1024);
        bfrag B2 = *(const bfrag*)(lt + lane * 16 + 2048);
        bfrag B3 = *(const bfrag*)(lt + lane * 16 + 3072);
        c0 = z; c1 = z;
        c0 = __builtin_amdgcn_mfma_f32_16x16x32_bf16(A[0][0], B0, c0, 0, 0, 0);
        c1 = __builtin_amdgcn_mfma_f32_16x16x32_bf16(A[1][0], B0, c1, 0, 0, 0);
        c0 = __builtin_amdgcn_mfma_f32_16x16x32_bf16(A[0][1], B1, c0, 0, 0, 0);
        c1 = __builtin_amdgcn_mfma_f32_16x16x32_bf16(A[1][1], B1, c1, 0, 0, 0);
        c0 = __builtin_amdgcn_mfma_f32_16x16x32_bf16(A[0][2], B2, c0, 0, 0, 0);
        c1 = __builtin_amdgcn_mfma_f32_16x16x32_bf16(A[1][2], B2, c1, 0, 0, 0);
        c0 = __builtin_amdgcn_mfma_f32_16x16x32_bf16(A[0][3], B3, c0, 0, 0, 0);
        c1 = __builtin_amdgcn_mfma_f32_16x16x32_bf16(A[1][3], B3, c1, 0, 0, 0);
    };

    f32x4 c0, c1;

    // W1: chunks 0..15, rows 2j,2j+1 -> acc_s
    {
        f32x4 p0a, p0b, p1a, p1b;
        stage(0);
        loadw(0, p0a, p0b); loadw(1, p1a, p1b);
#pragma unroll 1
        for (int j = 0; j < 16; ++j) {
            const char* buf = nextbuf(j < 15 ? j + 1 : 16);
            f32x4 w0a = p0a, w0b = p0b, w1a = p1a, w1b = p1b;
            int nr = (j < 15) ? (2 * j + 2) : 0;
            loadw(nr, p0a, p0b); loadw(nr + 1, p1a, p1b);
            tile(buf,         c0, c1); acc_s0[0] += c0 * w0a; acc_s0[1] += c1 * w0b;
            tile(buf + 4096,  c0, c1); acc_s1[0] += c0 * w0a; acc_s1[1] += c1 * w0b;
            tile(buf + 8192,  c0, c1); acc_s0[0] += c0 * w1a; acc_s0[1] += c1 * w1b;
            tile(buf + 12288, c0, c1); acc_s1[0] += c0 * w1a; acc_s1[1] += c1 * w1b;
        }
    }
    // W2: chunks 16..23, rows 4j..4j+3 -> acc_g
    {
        f32x4 pa[4], pb[4];
#pragma unroll
        for (int i = 0; i < 4; ++i) loadw(i, pa[i], pb[i]);
#pragma unroll 1
        for (int j = 0; j < 8; ++j) {
            const char* buf = nextbuf(j < 7 ? 17 + j : 24);
            f32x4 wa[4], wb[4];
#pragma unroll
            for (int i = 0; i < 4; ++i) { wa[i] = pa[i]; wb[i] = pb[i]; }
            int nr = (j < 7) ? (4 * j + 4) : 32;
#pragma unroll
            for (int i = 0; i < 4; ++i) loadw(nr + i, pa[i], pb[i]);
#pragma unroll
            for (int i = 0; i < 4; ++i) {
                tile(buf + i * 4096, c0, c1);
                acc_g[0] += c0 * wa[i]; acc_g[1] += c1 * wb[i];
            }
        }
    }
    // W3: chunks 24..31, rows 32+2j,33+2j -> acc_s
    {
        f32x4 p0a, p0b, p1a, p1b;
        loadw(32, p0a, p0b); loadw(33, p1a, p1b);
#pragma unroll 1
        for (int j = 0; j < 8; ++j) {
            const char* buf = nextbuf(j < 7 ? 25 + j : 32);
            f32x4 w0a = p0a, w0b = p0b, w1a = p1a, w1b = p1b;
            int nr = (j < 7) ? (32 + 2 * j + 2) : 32;
            loadw(nr, p0a, p0b); loadw(nr + 1, p1a, p1b);
            tile(buf,         c0, c1); acc_s0[0] += c0 * w0a; acc_s0[1] += c1 * w0b;
            tile(buf + 4096,  c0, c1); acc_s1[0] += c0 * w0a; acc_s1[1] += c1 * w0b;
            tile(buf + 8192,  c0, c1); acc_s0[0] += c0 * w1a; acc_s0[1] += c1 * w1b;
            tile(buf + 12288, c0, c1); acc_s1[0] += c0 * w1a; acc_s1[1] += c1 * w1b;
        }
    }
    // W4: chunks 32..35, rows 32+4j+i -> acc_g
    {
        f32x4 pa[4], pb[4];
#pragma unroll
        for (int i = 0; i < 4; ++i) loadw(32 + i, pa[i], pb[i]);
#pragma unroll 1
        for (int j = 0; j < 4; ++j) {
            const char* buf = nextbuf(33 + j);   // 33,34,35,36
            f32x4 wa[4], wb[4];
#pragma unroll
            for (int i = 0; i < 4; ++i) { wa[i] = pa[i]; wb[i] = pb[i]; }
            int nr = (j < 3) ? (32 + 4 * j + 4) : 48;
#pragma unroll
            for (int i = 0; i < 4; ++i) loadw(nr + i, pa[i], pb[i]);
#pragma unroll
            for (int i = 0; i < 4; ++i) {
                tile(buf + i * 4096, c0, c1);
                acc_g[0] += c0 * wa[i]; acc_g[1] += c1 * wb[i];
            }
        }
    }
    // W5: chunks 36..43, rows 48+4j+i -> acc_t5
    {
        f32x4 pa[4], pb[4];
#pragma unroll
        for (int i = 0; i < 4; ++i) loadw(48 + i, pa[i], pb[i]);
#pragma unroll 1
        for (int j = 0; j < 8; ++j) {
            const char* buf = nextbuf(37 + j);   // 37..44
            f32x4 wa[4], wb[4];
#pragma unroll
            for (int i = 0; i < 4; ++i) { wa[i] = pa[i]; wb[i] = pb[i]; }
            int nr = (j < 7) ? (48 + 4 * j + 4) : 48;
#pragma unroll
            for (int i = 0; i < 4; ++i) loadw(nr + i, pa[i], pb[i]);
#pragma unroll
            for (int i = 0; i < 4; ++i) {
                tile(buf + i * 4096, c0, c1);
                acc_t5[0] += c0 * wa[i]; acc_t5[1] += c1 * wb[i];
            }
        }
    }
    // W6: chunks 44..47, u=4j+i, rows 80+3u+k -> acc_v[k]
    {
        f32x4 va[3], vb[3];
#pragma unroll
        for (int k = 0; k < 3; ++k) loadw(80 + k, va[k], vb[k]);
#pragma unroll 1
        for (int j = 0; j < 4; ++j) {
            const char* buf = nextbuf(j < 3 ? 45 + j : -1);
#pragma unroll
            for (int i = 0; i < 4; ++i) {
                f32x4 wa[3], wb[3];
#pragma unroll
                for (int k = 0; k < 3; ++k) { wa[k] = va[k]; wb[k] = vb[k]; }
                int un = 4 * j + i + 1; if (un > 15) un = 0;
#pragma unroll
                for (int k = 0; k < 3; ++k) loadw(80 + 3 * un + k, va[k], vb[k]);
                tile(buf + i * 4096, c0, c1);
#pragma unroll
                for (int k = 0; k < 3; ++k) {
                    acc_v[0][k] += c0 * wa[k];
                    acc_v[1][k] += c1 * wb[k];
                }
            }
        }
    }

    if (dup) return;
    // Epilogue: coalesced stores to msg[e][96] (v stored as [k][w] planes)
#pragma unroll
    for (int s = 0; s < 2; ++s) {
        long eb = e0 + s * 16 + quad * 4;
#pragma unroll
        for (int r = 0; r < 4; ++r) {
            long e = eb + r;
            float* m = msg + (size_t)e * 96;
            float y1a = Yij[4 * e + 1], y1b = Yij[4 * e + 2], y1c = Yij[4 * e + 3];
            m[col]      = N_0E_C * acc_s0[s][r];
            m[16 + col] = N_0E_C * acc_s1[s][r];
            m[32 + col] = N_0E_C * acc_g[s][r];
            float t5 = acc_t5[s][r];
            m[48 + col] = NV_C * (t5 * y1a + acc_v[s][0][r]);
            m[64 + col] = NV_C * (t5 * y1b + acc_v[s][1][r]);
            m[80 + col] = NV_C * (t5 * y1c + acc_v[s][2][r]);
        }
    }
}

// ---- per-node gather + mean + relu-gate + residual (no atomics)
__global__ __launch_bounds__(128) void k_final(
    const float* __restrict__ x, const float* __restrict__ msg,
    const int* __restrict__ hist, const int* __restrict__ off,
    const int* __restrict__ csr_e, float* __restrict__ out) {
    int n = blockIdx.x;
    int t = threadIdx.x;
    __shared__ float sm[96];
    int cnt = hist[n];
    int o = off[n];
    if (t < 96) {
        float s = 0.f;
        for (int j = 0; j < cnt; ++j) {
            int e = csr_e[o + j];
            s += msg[(size_t)e * 96 + t];
        }
        float m = (cnt > 0) ? (float)cnt : 1.0f;
        sm[t] = s / m;
    }
    __syncthreads();
    if (t < 80) {
        float val;
        if (t < 32) {
            val = SQRT2_C * fmaxf(sm[t], 0.f);
        } else {
            int j = t - 32, w = j / 3, k = j - 3 * w;
            float g = SQRT2_C * fmaxf(sm[32 + w], 0.f);
            val = sm[48 + k * 16 + w] * g;
        }
        out[(size_t)n * 80 + t] = x[(size_t)n * 80 + t] + val;
    }
}

extern "C" void kernel_launch(void* const* d_in, const int* in_sizes, int n_in,
                              void* d_out, int out_size, void* d_ws, size_t ws_size,
                              hipStream_t stream) {
    const float* x         = (const float*)d_in[0];
    const float* edge_attr = (const float*)d_in[1];
    const float* Yij       = (const float*)d_in[2];
    const int*   edge_index= (const int*)d_in[3];
    const float* w_emb     = (const float*)d_in[4];
    float* out = (float*)d_out;

    char* ws = (char*)d_ws;
    size_t off_b = 0;
    unsigned short* emb = (unsigned short*)(ws + off_b); off_b += (size_t)E_EDGES * 128 * 2;
    unsigned short* Bt  = (unsigned short*)(ws + off_b); off_b += (size_t)3072 * 128 * 2;
    off_b = (off_b + 255) & ~(size_t)255;
    float* rT   = (float*)(ws + off_b); off_b += (size_t)(E_EDGES / 32) * 4096 * 4;
    float* msg  = (float*)(ws + off_b); off_b += (size_t)E_EDGES * 96 * 4;
    int* hist   = (int*)(ws + off_b);   off_b += (size_t)NUM_NODES * 4;
    int* offv   = (int*)(ws + off_b);   off_b += (size_t)NUM_NODES * 4;
    int* pos    = (int*)(ws + off_b);   off_b += (size_t)NUM_NODES * 4;
    int* csr_e  = (int*)(ws + off_b);   off_b += (size_t)E_EDGES * 4;

    hipMemsetAsync(hist, 0, (size_t)NUM_NODES * 4, stream);
    k_wt  <<<(128 * 3072 + 255) / 256, 256, 0, stream>>>(w_emb, Bt);
    k_prep<<<(E_EDGES + 255) / 256, 256, 0, stream>>>(x, edge_attr, Yij, edge_index, emb, rT, hist);
    k_scan<<<1, 1024, 0, stream>>>(hist, offv, pos);
    k_fill<<<(E_EDGES + 255) / 256, 256, 0, stream>>>(edge_index, pos, csr_e);
    k_gemm<<<(E_EDGES + 127) / 128, 256, 0, stream>>>(emb, Bt, rT, Yij, msg);
    k_final<<<NUM_NODES, 128, 0, stream>>>(x, msg, hist, offv, csr_e, out);
}